// Round 18
// baseline (75.591 us; speedup 1.0000x reference)
//
#include <hip/hip_runtime.h>
#include <math.h>

// Problem constants
#define B_ 4
#define C_ 256
#define CO_ 256
#define H_ 64
#define W_ 64
#define HW_ 4096
#define KK_ 9   // 3x3 kernel positions
#define NCH_ 27 // 18 offset + 9 mask channels

typedef __attribute__((ext_vector_type(8))) short bf16x8;
typedef __attribute__((ext_vector_type(4))) float f32x4;
typedef __attribute__((ext_vector_type(2))) float f32x2;

__device__ inline unsigned short f32_to_bf16(float f) {
    unsigned int u = __float_as_uint(f);
    unsigned int r = (u + 0x7FFFu + ((u >> 16) & 1u)) >> 16;  // RNE
    return (unsigned short)r;
}

// ---------------------------------------------------------------------------
// Kernel 1: prep_all = transpose_x (bid<4096) + prep_weights (bid>=4096).
// Transpose vectorized: 1 float4 load + 1 ushort4 store per thread.
// weights -> bf16 pre-swizzled chunks; pos = (o<<6)+(((ck>>3)^(o&7))<<3)+(ck&7)
// ---------------------------------------------------------------------------
__global__ void prep_all(const float* __restrict__ x, unsigned short* __restrict__ xTh,
                         const float* __restrict__ w_dcn, const float* __restrict__ w_off,
                         const float* __restrict__ w_mask,
                         unsigned short* __restrict__ wTs, unsigned short* __restrict__ wCs) {
    __shared__ float tile[32][33];   // [c_local][hw_local], pad 33
    __shared__ float lw[2304];
    const int t = threadIdx.x;
    const int bid = blockIdx.x;
    if (bid < 4096) {
        const int b = bid >> 10;
        const int rem = bid & 1023;
        const int c0 = (rem >> 7) << 5;
        const int hw0 = (rem & 127) << 5;
        const float* xb = x + ((size_t)b << 20);
        unsigned short* xTb = xTh + ((size_t)b << 20);
        {
            int r = t >> 3, q = t & 7;
            float4 v = *(const float4*)(xb + ((size_t)(c0 + r) << 12) + hw0 + (q << 2));
            tile[r][(q << 2) + 0] = v.x;
            tile[r][(q << 2) + 1] = v.y;
            tile[r][(q << 2) + 2] = v.z;
            tile[r][(q << 2) + 3] = v.w;
        }
        __syncthreads();
        {
            int hw = t >> 3, c4 = t & 7;
            ushort4 o;
            o.x = f32_to_bf16(tile[(c4 << 2) + 0][hw]);
            o.y = f32_to_bf16(tile[(c4 << 2) + 1][hw]);
            o.z = f32_to_bf16(tile[(c4 << 2) + 2][hw]);
            o.w = f32_to_bf16(tile[(c4 << 2) + 3][hw]);
            *(ushort4*)(xTb + ((size_t)(hw0 + hw) << 8) + c0 + (c4 << 2)) = o;
        }
    } else if (bid < 4352) {
        const int o = bid - 4096;
        for (int e = t; e < 576; e += 256)
            ((float4*)lw)[e] = ((const float4*)(w_dcn + (size_t)o * 2304))[e];
        __syncthreads();
        for (int e = t; e < 2304; e += 256) {
            int k = e >> 8, c = e & 255;
            int chunk = (k << 2) + (c >> 6), ck = c & 63;
            int pos = (o << 6) + (((ck >> 3) ^ (o & 7)) << 3) + (ck & 7);
            wTs[(size_t)chunk * 16384 + pos] = f32_to_bf16(lw[c * 9 + k]);
        }
    } else {
        const int ch = bid - 4352;  // 0..31
        const float* src = (ch < 18) ? w_off + (size_t)ch * 2304
                         : (ch < NCH_) ? w_mask + (size_t)(ch - 18) * 2304
                         : nullptr;
        if (src) {
            for (int e = t; e < 576; e += 256) ((float4*)lw)[e] = ((const float4*)src)[e];
        } else {
            for (int e = t; e < 2304; e += 256) lw[e] = 0.f;
        }
        __syncthreads();
        for (int e = t; e < 2304; e += 256) {
            int k = e >> 8, c = e & 255;
            int chunk = (k << 2) + (c >> 6), ck = c & 63;
            int pos = (ch << 6) + (((ck >> 3) ^ (ch & 7)) << 3) + (ck & 7);
            wCs[(size_t)chunk * 2048 + pos] = f32_to_bf16(lw[c * 9 + k]);
        }
    }
}

// ---------------------------------------------------------------------------
// Kernel 2: offset+mask conv, counted-vmcnt, PAIRED chunks: 18 phases of
// 2 chunks each (4 MFMA/wave/phase), 1 barrier per phase.
// grid 512 (2 blocks/CU): b=(bid&7)>>1, ph2=bid&1, hh=bid>>3.
// Per phase: issue 2 xload + 2 wdma | vmcnt(2) | 2 xwrite | lgkm0 | barrier
// | compute(4 MFMA). LDS 3-slot x (2x2048) = 48 KB.
// ---------------------------------------------------------------------------
__global__ __launch_bounds__(256, 2) void conv_mfma(
    const unsigned short* __restrict__ xTh, const unsigned short* __restrict__ wCs,
    const float* __restrict__ b_off, const float* __restrict__ b_mask,
    float* __restrict__ offmask) {
    __shared__ alignas(16) unsigned short wlds[3][4096];   // 24 KB
    __shared__ alignas(16) unsigned short xlds[3][4096];   // 24 KB
    const int t = threadIdx.x;
    const int bid = blockIdx.x;
    const int b = (bid & 7) >> 1;
    const int ph2 = bid & 1;
    const int hh = bid >> 3;
    const unsigned short* xb = xTh + ((size_t)b << 20);

    auto stage_w2 = [&](int phase, int slot) {
#pragma unroll
        for (int sub = 0; sub < 2; ++sub) {
            int chunk = (phase << 1) + sub;
            const unsigned short* g = wCs + ((size_t)chunk << 11) + (t << 3);
            __builtin_amdgcn_global_load_lds(
                (const __attribute__((address_space(1))) unsigned int*)g,
                (__attribute__((address_space(3))) unsigned int*)&wlds[slot][(sub << 11) + (t << 3)],
                16, 0, 0);
        }
    };

    const int xp = t >> 3, xcs = t & 7;   // 32 p x 8 c-octs
    auto xload1 = [&](int chunk, uint4& xr, bool& xv) {
        int k = chunk >> 2, cc = chunk & 3;
        int ki = k / 3, kj = k % 3;
        int py = hh + ki - 1;
        int px = (ph2 << 5) + xp + kj - 1;
        xv = (py >= 0) & (py < H_) & (px >= 0) & (px < W_);
        int pyc = min(max(py, 0), 63), pxc = min(max(px, 0), 63);
        xr = *(const uint4*)(xb + (((size_t)((pyc << 6) + pxc)) << 8) + (cc << 6) + (xcs << 3));
    };
    auto xwrite1 = [&](int slot, int sub, const uint4& xr, bool xv) {
        uint4 u = xv ? xr : make_uint4(0u, 0u, 0u, 0u);
        *(uint4*)&xlds[slot][(sub << 11) + (xp << 6) + ((xcs ^ (xp & 7)) << 3)] = u;
    };

    const int wid = t >> 6, lane = t & 63;
    const int wc = wid >> 1, wp = wid & 1;
    const int m16 = lane & 15, kg = lane >> 4;
    f32x4 acc = {};

    auto compute2 = [&](int slot) {
#pragma unroll
        for (int sub = 0; sub < 2; ++sub)
#pragma unroll
            for (int ks = 0; ks < 2; ++ks) {
                int s = (ks << 2) + kg;
                int o = (wc << 4) + m16;
                bf16x8 a = *(const bf16x8*)&wlds[slot][(sub << 11) + (o << 6) + ((s ^ (o & 7)) << 3)];
                int p = (wp << 4) + m16;
                bf16x8 bf = *(const bf16x8*)&xlds[slot][(sub << 11) + (p << 6) + ((s ^ (p & 7)) << 3)];
                acc = __builtin_amdgcn_mfma_f32_16x16x32_bf16(a, bf, acc, 0, 0, 0);
            }
    };

    uint4 xr0, xr1;
    bool xv0, xv1;

    // prologue: phase 0 (chunks 0,1); issue order: 2 xload then 2 wdma
    xload1(0, xr0, xv0);
    xload1(1, xr1, xv1);
    stage_w2(0, 0);
    asm volatile("s_waitcnt vmcnt(2)" ::: "memory");   // retire xloads, keep 2 wdma
    xwrite1(0, 0, xr0, xv0);
    xwrite1(0, 1, xr1, xv1);

    for (int ph = 0; ph < 17; ++ph) {
        xload1((ph << 1) + 2, xr0, xv0);               // +1 VMEM
        xload1((ph << 1) + 3, xr1, xv1);               // +1 VMEM
        stage_w2(ph + 1, (ph + 1) % 3);                // +2 VMEM (newest)
        // outstanding: wdma(ph)x2, xload x2, wdma(ph+1)x2 -> keep newest 2
        asm volatile("s_waitcnt vmcnt(2)" ::: "memory");
        xwrite1((ph + 1) % 3, 0, xr0, xv0);
        xwrite1((ph + 1) % 3, 1, xr1, xv1);
        asm volatile("s_waitcnt lgkmcnt(0)" ::: "memory");
        __builtin_amdgcn_s_barrier();
        asm volatile("" ::: "memory");
        compute2(ph % 3);
    }
    asm volatile("s_waitcnt vmcnt(0)" ::: "memory");
    asm volatile("s_waitcnt lgkmcnt(0)" ::: "memory");
    __builtin_amdgcn_s_barrier();
    asm volatile("" ::: "memory");
    compute2(17 % 3);

    const int pix = (hh << 6) + (ph2 << 5) + (wp << 4) + m16;
#pragma unroll
    for (int r = 0; r < 4; ++r) {
        int ch = (wc << 4) + (kg << 2) + r;
        if (ch < NCH_) {
            float bias = (ch < 18) ? b_off[ch] : b_mask[ch - 18];
            offmask[(((size_t)b * NCH_ + ch) << 12) + pix] = acc[r] + bias;
        }
    }
}

// ---------------------------------------------------------------------------
// Kernel 3: fused sample + bf16 MFMA GEMM, K-SPLIT x2, 2 blocks/CU.
// v2: coords in REGISTERS (9 per thread for its pq), vbuf DOUBLE-buffered,
// SINGLE barrier per chunk; stage_w issued after the barrier (overlaps MFMA,
// WAR-safe: barrier(c) guarantees compute(c-1) done before w(c+1) overwrite).
// Per chunk: gather(c+1) | vmcnt(8) | finish(c) | vmcnt(4)+lgkm0 | barrier |
// stage_w(c+1) | MFMA(c).  LDS: 65536 + 16384 = 81920 B -> exactly 2/CU.
// ---------------------------------------------------------------------------
__global__ __launch_bounds__(512, 4) void dcn_fused(
    const unsigned short* __restrict__ xTh, const float* __restrict__ offmask,
    const unsigned short* __restrict__ wTs, unsigned short* __restrict__ part) {
    __shared__ alignas(16) unsigned short wbuf[2][16384];   // 65536 B
    __shared__ alignas(16) unsigned short vbuf[2][4096];    // 16384 B

    const int t = threadIdx.x;
    const int bid = blockIdx.x;
    const int b = (bid & 7) >> 1;
    const int half = bid & 1;
    const int tile64 = bid >> 3;        // 0..63
    const int pix0 = tile64 << 6;
    const unsigned short* xb = xTh + ((size_t)b << 20);
    const float* omb = offmask + (((size_t)b * NCH_) << 12);

    const int oct = t & 7, pq = t >> 3;   // producer: 8 c-octs x 64 pixels
    const int wid = t >> 6, lane = t & 63;
    const int wo = wid >> 1, wp = wid & 1;
    const int m16 = lane & 15, kg = lane >> 4;
    const int vslot = (pq << 6) + ((oct ^ (pq & 7)) << 3);

    // ---- per-thread coords for pixel pq: 9 k (8x dup across octs, one-time)
    ushort4 cwhR[9];
    uchar4 coffR[9];
    {
        const int pixq = pix0 + pq;
        const int hhq = pixq >> 6, wwq = pixq & 63;
#pragma unroll
        for (int k = 0; k < 9; ++k) {
            float dy = omb[((size_t)(2 * k) << 12) + pixq];
            float dx = omb[((size_t)(2 * k + 1) << 12) + pixq];
            float ml = omb[((size_t)(18 + k) << 12) + pixq];
            float m = 1.f / (1.f + __expf(-ml));
            float py = (float)(hhq - 1 + (k / 3)) + dy;
            float px = (float)(wwq - 1 + (k % 3)) + dx;
            float fy0 = floorf(py), fx0 = floorf(px);
            float ay = py - fy0, ax = px - fx0;
            bool y0v = (fy0 >= 0.f) && (fy0 <= 63.f);
            bool y1v = (fy0 >= -1.f) && (fy0 <= 62.f);
            bool x0v = (fx0 >= 0.f) && (fx0 <= 63.f);
            bool x1v = (fx0 >= -1.f) && (fx0 <= 62.f);
            int y0 = (int)fy0, x0 = (int)fx0;
            int iy0 = min(max(y0, 0), 63), iy1 = min(max(y0 + 1, 0), 63);
            int ix0 = min(max(x0, 0), 63), ix1 = min(max(x0 + 1, 0), 63);
            float w00 = (y0v && x0v) ? m * (1.f - ay) * (1.f - ax) : 0.f;
            float w01 = (y0v && x1v) ? m * (1.f - ay) * ax : 0.f;
            float w10 = (y1v && x0v) ? m * ay * (1.f - ax) : 0.f;
            float w11 = (y1v && x1v) ? m * ay * ax : 0.f;
            cwhR[k] = make_ushort4(f32_to_bf16(w00), f32_to_bf16(w01),
                                   f32_to_bf16(w10), f32_to_bf16(w11));
            coffR[k] = make_uchar4((unsigned char)iy0, (unsigned char)ix0,
                                   (unsigned char)iy1, (unsigned char)ix1);
        }
    }

    // local chunk c (0..17) -> global chunk gc = (c>>1)*4 + half*2 + (c&1)
    auto stage_w = [&](int c, int slot) {
        int gc = ((c >> 1) << 2) + (half << 1) + (c & 1);
#pragma unroll
        for (int r = 0; r < 4; ++r) {
            int off16 = (r << 9) + t;   // 16B units
            const unsigned short* g = wTs + ((size_t)gc << 14) + (off16 << 3);
            __builtin_amdgcn_global_load_lds(
                (const __attribute__((address_space(1))) unsigned int*)g,
                (__attribute__((address_space(3))) unsigned int*)&wbuf[slot][off16 << 3], 16, 0, 0);
        }
    };

    auto gather = [&](int c, uint4* g) {
        int k = c >> 1, cc = (half << 1) + (c & 1);
        uchar4 q = coffR[k];
        const unsigned short* cb = xb + (cc << 6) + (oct << 3);
        g[0] = *(const uint4*)(cb + ((((int)q.x << 6) + q.y) << 8));
        g[1] = *(const uint4*)(cb + ((((int)q.x << 6) + q.w) << 8));
        g[2] = *(const uint4*)(cb + ((((int)q.z << 6) + q.y) << 8));
        g[3] = *(const uint4*)(cb + ((((int)q.z << 6) + q.w) << 8));
    };

    auto finish = [&](int c, const uint4* g) {
        int k = c >> 1;
        ushort4 wv = cwhR[k];
        float w0 = __uint_as_float((unsigned int)wv.x << 16);
        float w1 = __uint_as_float((unsigned int)wv.y << 16);
        float w2 = __uint_as_float((unsigned int)wv.z << 16);
        float w3 = __uint_as_float((unsigned int)wv.w << 16);
        union { uint4 v; unsigned int u[4]; } A, B2, C2, D2;
        A.v = g[0]; B2.v = g[1]; C2.v = g[2]; D2.v = g[3];
        unsigned int o4[4];
#pragma unroll
        for (int j = 0; j < 4; ++j) {
            f32x2 a2 = {__uint_as_float(A.u[j] << 16),  __uint_as_float(A.u[j] & 0xffff0000u)};
            f32x2 b2 = {__uint_as_float(B2.u[j] << 16), __uint_as_float(B2.u[j] & 0xffff0000u)};
            f32x2 c2 = {__uint_as_float(C2.u[j] << 16), __uint_as_float(C2.u[j] & 0xffff0000u)};
            f32x2 d2 = {__uint_as_float(D2.u[j] << 16), __uint_as_float(D2.u[j] & 0xffff0000u)};
            f32x2 v2 = a2 * w0 + b2 * w1 + c2 * w2 + d2 * w3;   // v_pk_fma_f32
            unsigned int pk;
            asm("v_cvt_pk_bf16_f32 %0, %1, %2" : "=v"(pk) : "v"(v2.x), "v"(v2.y));
            o4[j] = pk;
        }
        *(uint4*)&vbuf[c & 1][vslot] = make_uint4(o4[0], o4[1], o4[2], o4[3]);
    };

    f32x4 acc[4][2] = {};

    auto compute = [&](int slot) {
#pragma unroll
        for (int ks = 0; ks < 2; ++ks) {
            int s = (ks << 2) + kg;
            bf16x8 aF[4], bF[2];
#pragma unroll
            for (int i = 0; i < 4; ++i) {
                int o = (wo << 6) + (i << 4) + m16;
                aF[i] = *(const bf16x8*)&wbuf[slot][(o << 6) + ((s ^ (o & 7)) << 3)];
            }
#pragma unroll
            for (int j = 0; j < 2; ++j) {
                int p = (wp << 5) + (j << 4) + m16;   // 0..63
                bF[j] = *(const bf16x8*)&vbuf[slot][(p << 6) + ((s ^ (p & 7)) << 3)];
            }
#pragma unroll
            for (int i = 0; i < 4; ++i)
#pragma unroll
                for (int j = 0; j < 2; ++j)
                    acc[i][j] = __builtin_amdgcn_mfma_f32_16x16x32_bf16(
                        aF[i], bF[j], acc[i][j], 0, 0, 0);
        }
    };

    uint4 gA[4], gB[4];

    // prologue: g(0), w(0) in flight (8 VMEM/wave)
    gather(0, gA);
    stage_w(0, 0);

    // Steady per chunk c: g(c+1) issue | vmcnt(8) retire g(c) |
    // finish(c)->vbuf[c&1] | vmcnt(4)+lgkm0 retire w(c) | barrier |
    // stage_w(c+1)->wbuf[(c+1)&1] | compute(c). Tail: (4,0).
#define HALFSTEP(CUR, GCUR, GNXT, NWA, NWB)                              \
    if ((CUR) + 1 < 18) gather((CUR) + 1, GNXT);                         \
    asm volatile("s_waitcnt vmcnt(" #NWA ")" ::: "memory");              \
    finish((CUR), GCUR);                                                 \
    asm volatile("s_waitcnt vmcnt(" #NWB ") lgkmcnt(0)" ::: "memory");   \
    __builtin_amdgcn_s_barrier();                                        \
    asm volatile("" ::: "memory");                                       \
    if ((CUR) + 1 < 18) stage_w((CUR) + 1, ((CUR) + 1) & 1);             \
    __builtin_amdgcn_s_setprio(1);                                       \
    compute((CUR) & 1);                                                  \
    __builtin_amdgcn_s_setprio(0);

    for (int c = 0; c < 16; c += 2) {
        HALFSTEP(c, gA, gB, 8, 4)
        HALFSTEP(c + 1, gB, gA, 8, 4)
    }
    HALFSTEP(16, gA, gB, 8, 4)
    HALFSTEP(17, gB, gA, 4, 0)
#undef HALFSTEP

    // partial write: part[half][b][o][p], bf16, no bias
    unsigned short* pd = part + (((size_t)((half << 2) + b)) << 20);
#pragma unroll
    for (int i = 0; i < 4; ++i) {
        int ob = (wo << 6) + (i << 4) + (kg << 2);
#pragma unroll
        for (int j = 0; j < 2; ++j) {
            int p = pix0 + (wp << 5) + (j << 4) + m16;
#pragma unroll
            for (int r = 0; r < 4; ++r) {
                int oo = ob + r;
                pd[(((size_t)oo) << 12) + p] = f32_to_bf16(acc[i][j][r]);
            }
        }
    }
}

// ---------------------------------------------------------------------------
// Kernel 4: combine bf16 partials + bias: out = p0 + p1 + b_dcn[o]. f32 out.
// ---------------------------------------------------------------------------
__global__ __launch_bounds__(256) void combine_out(
    const unsigned short* __restrict__ part, const float* __restrict__ b_dcn,
    float* __restrict__ out) {
    int i = (blockIdx.x * 256 + threadIdx.x) << 3;
    float bias = b_dcn[(i >> 12) & 255];
    union { uint4 v; unsigned int u[4]; } A, B2;
    A.v  = *(const uint4*)(part + i);
    B2.v = *(const uint4*)(part + ((size_t)4 << 20) + i);
    float r[8];
#pragma unroll
    for (int j = 0; j < 4; ++j) {
        float a_lo = __uint_as_float(A.u[j] << 16);
        float a_hi = __uint_as_float(A.u[j] & 0xffff0000u);
        float b_lo = __uint_as_float(B2.u[j] << 16);
        float b_hi = __uint_as_float(B2.u[j] & 0xffff0000u);
        r[2 * j]     = a_lo + b_lo + bias;
        r[2 * j + 1] = a_hi + b_hi + bias;
    }
    *(float4*)(out + i)     = make_float4(r[0], r[1], r[2], r[3]);
    *(float4*)(out + i + 4) = make_float4(r[4], r[5], r[6], r[7]);
}

// ---------------------------------------------------------------------------
extern "C" void kernel_launch(void* const* d_in, const int* in_sizes, int n_in,
                              void* d_out, int out_size, void* d_ws, size_t ws_size,
                              hipStream_t stream) {
    const float* x      = (const float*)d_in[0];
    const float* w_off  = (const float*)d_in[1];
    const float* b_off  = (const float*)d_in[2];
    const float* w_mask = (const float*)d_in[3];
    const float* b_mask = (const float*)d_in[4];
    const float* w_dcn  = (const float*)d_in[5];
    const float* b_dcn  = (const float*)d_in[6];
    float* out = (float*)d_out;

    float* ws = (float*)d_ws;
    float* offmask = ws;                                       //  1.77 MB
    unsigned short* xTh = (unsigned short*)(offmask + (size_t)B_ * NCH_ * HW_); // 8.39 MB
    unsigned short* wTs = xTh + ((size_t)B_ * HW_ * C_);       //  1.18 MB
    unsigned short* wCs = wTs + (size_t)36 * 16384;            //  0.15 MB
    unsigned short* part = wCs + (size_t)36 * 2048;            // 16.78 MB (2 halves, bf16)
    // total ~28.3 MB of d_ws

    prep_all<<<dim3(4384), dim3(256), 0, stream>>>(x, xTh, w_dcn, w_off, w_mask, wTs, wCs);
    conv_mfma<<<dim3(512), dim3(256), 0, stream>>>(xTh, wCs, b_off, b_mask, offmask);
    dcn_fused<<<dim3(512), dim3(512), 0, stream>>>(xTh, offmask, wTs, part);
    combine_out<<<dim3(2048), dim3(256), 0, stream>>>(part, b_dcn, out);
}

// Round 19
// 71.615 us; speedup vs baseline: 1.0555x; 1.0555x over previous
//
#include <hip/hip_runtime.h>
#include <math.h>

// Problem constants
#define B_ 4
#define C_ 256
#define CO_ 256
#define H_ 64
#define W_ 64
#define HW_ 4096
#define KK_ 9   // 3x3 kernel positions
#define NCH_ 27 // 18 offset + 9 mask channels

typedef __attribute__((ext_vector_type(8))) short bf16x8;
typedef __attribute__((ext_vector_type(4))) float f32x4;
typedef __attribute__((ext_vector_type(2))) float f32x2;

__device__ inline unsigned short f32_to_bf16(float f) {
    unsigned int u = __float_as_uint(f);
    unsigned int r = (u + 0x7FFFu + ((u >> 16) & 1u)) >> 16;  // RNE
    return (unsigned short)r;
}

// ---------------------------------------------------------------------------
// Kernel 1: prep_all = transpose_x (bid<4096) + prep_weights (bid>=4096).
// Transpose vectorized: 1 float4 load + 1 ushort4 store per thread.
// weights -> bf16 pre-swizzled chunks; pos = (o<<6)+(((ck>>3)^(o&7))<<3)+(ck&7)
// ---------------------------------------------------------------------------
__global__ void prep_all(const float* __restrict__ x, unsigned short* __restrict__ xTh,
                         const float* __restrict__ w_dcn, const float* __restrict__ w_off,
                         const float* __restrict__ w_mask,
                         unsigned short* __restrict__ wTs, unsigned short* __restrict__ wCs) {
    __shared__ float tile[32][33];   // [c_local][hw_local], pad 33
    __shared__ float lw[2304];
    const int t = threadIdx.x;
    const int bid = blockIdx.x;
    if (bid < 4096) {
        const int b = bid >> 10;
        const int rem = bid & 1023;
        const int c0 = (rem >> 7) << 5;
        const int hw0 = (rem & 127) << 5;
        const float* xb = x + ((size_t)b << 20);
        unsigned short* xTb = xTh + ((size_t)b << 20);
        {
            int r = t >> 3, q = t & 7;
            float4 v = *(const float4*)(xb + ((size_t)(c0 + r) << 12) + hw0 + (q << 2));
            tile[r][(q << 2) + 0] = v.x;
            tile[r][(q << 2) + 1] = v.y;
            tile[r][(q << 2) + 2] = v.z;
            tile[r][(q << 2) + 3] = v.w;
        }
        __syncthreads();
        {
            int hw = t >> 3, c4 = t & 7;
            ushort4 o;
            o.x = f32_to_bf16(tile[(c4 << 2) + 0][hw]);
            o.y = f32_to_bf16(tile[(c4 << 2) + 1][hw]);
            o.z = f32_to_bf16(tile[(c4 << 2) + 2][hw]);
            o.w = f32_to_bf16(tile[(c4 << 2) + 3][hw]);
            *(ushort4*)(xTb + ((size_t)(hw0 + hw) << 8) + c0 + (c4 << 2)) = o;
        }
    } else if (bid < 4352) {
        const int o = bid - 4096;
        for (int e = t; e < 576; e += 256)
            ((float4*)lw)[e] = ((const float4*)(w_dcn + (size_t)o * 2304))[e];
        __syncthreads();
        for (int e = t; e < 2304; e += 256) {
            int k = e >> 8, c = e & 255;
            int chunk = (k << 2) + (c >> 6), ck = c & 63;
            int pos = (o << 6) + (((ck >> 3) ^ (o & 7)) << 3) + (ck & 7);
            wTs[(size_t)chunk * 16384 + pos] = f32_to_bf16(lw[c * 9 + k]);
        }
    } else {
        const int ch = bid - 4352;  // 0..31
        const float* src = (ch < 18) ? w_off + (size_t)ch * 2304
                         : (ch < NCH_) ? w_mask + (size_t)(ch - 18) * 2304
                         : nullptr;
        if (src) {
            for (int e = t; e < 576; e += 256) ((float4*)lw)[e] = ((const float4*)src)[e];
        } else {
            for (int e = t; e < 2304; e += 256) lw[e] = 0.f;
        }
        __syncthreads();
        for (int e = t; e < 2304; e += 256) {
            int k = e >> 8, c = e & 255;
            int chunk = (k << 2) + (c >> 6), ck = c & 63;
            int pos = (ch << 6) + (((ck >> 3) ^ (ch & 7)) << 3) + (ck & 7);
            wCs[(size_t)chunk * 2048 + pos] = f32_to_bf16(lw[c * 9 + k]);
        }
    }
}

// ---------------------------------------------------------------------------
// Kernel 2: offset+mask conv, counted-vmcnt 1-barrier/chunk schedule.
// grid 512 (2 blocks/CU): b=(bid&7)>>1, ph=bid&1, hh=bid>>3.
// ---------------------------------------------------------------------------
__global__ __launch_bounds__(256, 2) void conv_mfma(
    const unsigned short* __restrict__ xTh, const unsigned short* __restrict__ wCs,
    const float* __restrict__ b_off, const float* __restrict__ b_mask,
    float* __restrict__ offmask) {
    __shared__ alignas(16) unsigned short wlds[3][2048];   // 12 KB
    __shared__ alignas(16) unsigned short xlds[3][2048];   // 12 KB
    const int t = threadIdx.x;
    const int bid = blockIdx.x;
    const int b = (bid & 7) >> 1;
    const int ph = bid & 1;
    const int hh = bid >> 3;
    const unsigned short* xb = xTh + ((size_t)b << 20);

    auto stage_w = [&](int chunk, int slot) {
        const unsigned short* g = wCs + ((size_t)chunk << 11) + (t << 3);
        __builtin_amdgcn_global_load_lds(
            (const __attribute__((address_space(1))) unsigned int*)g,
            (__attribute__((address_space(3))) unsigned int*)&wlds[slot][t << 3], 16, 0, 0);
    };

    const int xp = t >> 3, xcs = t & 7;   // 32 p x 8 c-octs
    uint4 xr;
    bool xvalid;
    auto xload = [&](int chunk) {
        int k = chunk >> 2, cc = chunk & 3;
        int ki = k / 3, kj = k % 3;
        int py = hh + ki - 1;
        int px = (ph << 5) + xp + kj - 1;
        xvalid = (py >= 0) & (py < H_) & (px >= 0) & (px < W_);
        int pyc = min(max(py, 0), 63), pxc = min(max(px, 0), 63);
        xr = *(const uint4*)(xb + (((size_t)((pyc << 6) + pxc)) << 8) + (cc << 6) + (xcs << 3));
    };
    auto xwrite = [&](int slot) {
        uint4 u = xvalid ? xr : make_uint4(0u, 0u, 0u, 0u);
        *(uint4*)&xlds[slot][(xp << 6) + ((xcs ^ (xp & 7)) << 3)] = u;
    };

    const int wid = t >> 6, lane = t & 63;
    const int wc = wid >> 1, wp = wid & 1;
    const int m16 = lane & 15, kg = lane >> 4;
    f32x4 acc = {};

    auto compute = [&](int slot) {
#pragma unroll
        for (int ks = 0; ks < 2; ++ks) {
            int s = (ks << 2) + kg;
            int o = (wc << 4) + m16;
            bf16x8 a = *(const bf16x8*)&wlds[slot][(o << 6) + ((s ^ (o & 7)) << 3)];
            int p = (wp << 4) + m16;
            bf16x8 bf = *(const bf16x8*)&xlds[slot][(p << 6) + ((s ^ (p & 7)) << 3)];
            acc = __builtin_amdgcn_mfma_f32_16x16x32_bf16(a, bf, acc, 0, 0, 0);
        }
    };

    // prologue: chunk 0 (issue order: xload first, wdma second)
    xload(0);
    stage_w(0, 0);
    asm volatile("s_waitcnt vmcnt(1)" ::: "memory");   // retire xload(0), keep wdma(0)
    xwrite(0);

    for (int c = 0; c < 35; ++c) {
        xload(c + 1);                       // 1 VMEM
        stage_w(c + 1, (c + 1) % 3);        // 1 VMEM (newest)
        // outstanding: wdma(c), xload(c+1), wdma(c+1) -> keep newest only
        asm volatile("s_waitcnt vmcnt(1)" ::: "memory");
        xwrite((c + 1) % 3);
        asm volatile("s_waitcnt lgkmcnt(0)" ::: "memory");
        __builtin_amdgcn_s_barrier();
        asm volatile("" ::: "memory");
        compute(c % 3);
    }
    asm volatile("s_waitcnt vmcnt(0)" ::: "memory");   // retire wdma(35)
    asm volatile("s_waitcnt lgkmcnt(0)" ::: "memory");
    __builtin_amdgcn_s_barrier();
    asm volatile("" ::: "memory");
    compute(35 % 3);

    const int pix = (hh << 6) + (ph << 5) + (wp << 4) + m16;
#pragma unroll
    for (int r = 0; r < 4; ++r) {
        int ch = (wc << 4) + (kg << 2) + r;
        if (ch < NCH_) {
            float bias = (ch < 18) ? b_off[ch] : b_mask[ch - 18];
            offmask[(((size_t)b * NCH_ + ch) << 12) + pix] = acc[r] + bias;
        }
    }
}

// ---------------------------------------------------------------------------
// Kernel 3: fused sample + bf16 MFMA GEMM, K-SPLIT x2 over c, 2 blocks/CU.
// grid 512: b=(bid&7)>>1, half=bid&1, tile64=bid>>3. bf16 partial outputs.
// Finish uses packed f32x2 math (v_pk_fma_f32). Schedule = proven R13.
// LDS: 4608 + 2304 + 65536 + 8192 = 80640 B -> 2/CU.
// ---------------------------------------------------------------------------
__global__ __launch_bounds__(512, 4) void dcn_fused(
    const unsigned short* __restrict__ xTh, const float* __restrict__ offmask,
    const unsigned short* __restrict__ wTs, unsigned short* __restrict__ part) {
    __shared__ ushort4 cwh[576];                            //  4608 B
    __shared__ uchar4 coffb[576];                           //  2304 B
    __shared__ alignas(16) unsigned short wbuf[2][16384];   // 65536 B
    __shared__ alignas(16) unsigned short vbuf[4096];       //  8192 B

    const int t = threadIdx.x;
    const int bid = blockIdx.x;
    const int b = (bid & 7) >> 1;
    const int half = bid & 1;
    const int tile64 = bid >> 3;        // 0..63
    const int pix0 = tile64 << 6;
    const unsigned short* xb = xTh + ((size_t)b << 20);
    const float* omb = offmask + (((size_t)b * NCH_) << 12);

    // ---- coords: 9 k x 64 p: bilinear weights (mask folded, bf16) + corners
    for (int e = t; e < 576; e += 512) {
        int k = e >> 6, p = e & 63;
        int pix = pix0 + p;
        int hh = pix >> 6, ww = pix & 63;
        float dy = omb[((size_t)(2 * k) << 12) + pix];
        float dx = omb[((size_t)(2 * k + 1) << 12) + pix];
        float ml = omb[((size_t)(18 + k) << 12) + pix];
        float m = 1.f / (1.f + __expf(-ml));
        float py = (float)(hh - 1 + (k / 3)) + dy;
        float px = (float)(ww - 1 + (k % 3)) + dx;
        float fy0 = floorf(py), fx0 = floorf(px);
        float ay = py - fy0, ax = px - fx0;
        bool y0v = (fy0 >= 0.f) && (fy0 <= 63.f);
        bool y1v = (fy0 >= -1.f) && (fy0 <= 62.f);
        bool x0v = (fx0 >= 0.f) && (fx0 <= 63.f);
        bool x1v = (fx0 >= -1.f) && (fx0 <= 62.f);
        int y0 = (int)fy0, x0 = (int)fx0;
        int iy0 = min(max(y0, 0), 63), iy1 = min(max(y0 + 1, 0), 63);
        int ix0 = min(max(x0, 0), 63), ix1 = min(max(x0 + 1, 0), 63);
        float w00 = (y0v && x0v) ? m * (1.f - ay) * (1.f - ax) : 0.f;
        float w01 = (y0v && x1v) ? m * (1.f - ay) * ax : 0.f;
        float w10 = (y1v && x0v) ? m * ay * (1.f - ax) : 0.f;
        float w11 = (y1v && x1v) ? m * ay * ax : 0.f;
        cwh[e] = make_ushort4(f32_to_bf16(w00), f32_to_bf16(w01),
                              f32_to_bf16(w10), f32_to_bf16(w11));
        coffb[e] = make_uchar4((unsigned char)iy0, (unsigned char)ix0,
                               (unsigned char)iy1, (unsigned char)ix1);
    }

    const int oct = t & 7, pq = t >> 3;   // producer: 8 c-octs x 64 pixels
    const int wid = t >> 6, lane = t & 63;
    const int wo = wid >> 1, wp = wid & 1;
    const int m16 = lane & 15, kg = lane >> 4;
    const int vslot = (pq << 6) + ((oct ^ (pq & 7)) << 3);

    // local chunk c (0..17) -> global chunk gc = (c>>1)*4 + half*2 + (c&1)
    auto stage_w = [&](int c, int slot) {
        int gc = ((c >> 1) << 2) + (half << 1) + (c & 1);
#pragma unroll
        for (int r = 0; r < 4; ++r) {
            int off16 = (r << 9) + t;   // 16B units
            const unsigned short* g = wTs + ((size_t)gc << 14) + (off16 << 3);
            __builtin_amdgcn_global_load_lds(
                (const __attribute__((address_space(1))) unsigned int*)g,
                (__attribute__((address_space(3))) unsigned int*)&wbuf[slot][off16 << 3], 16, 0, 0);
        }
    };

    auto gather = [&](int c, uint4* g) {
        int k = c >> 1, cc = (half << 1) + (c & 1);
        uchar4 q = coffb[(k << 6) + pq];
        const unsigned short* cb = xb + (cc << 6) + (oct << 3);
        g[0] = *(const uint4*)(cb + ((((int)q.x << 6) + q.y) << 8));
        g[1] = *(const uint4*)(cb + ((((int)q.x << 6) + q.w) << 8));
        g[2] = *(const uint4*)(cb + ((((int)q.z << 6) + q.y) << 8));
        g[3] = *(const uint4*)(cb + ((((int)q.z << 6) + q.w) << 8));
    };

    auto finish = [&](int c, const uint4* g) {
        int k = c >> 1;
        ushort4 wv = cwh[(k << 6) + pq];
        float w0 = __uint_as_float((unsigned int)wv.x << 16);
        float w1 = __uint_as_float((unsigned int)wv.y << 16);
        float w2 = __uint_as_float((unsigned int)wv.z << 16);
        float w3 = __uint_as_float((unsigned int)wv.w << 16);
        union { uint4 v; unsigned int u[4]; } A, B2, C2, D2;
        A.v = g[0]; B2.v = g[1]; C2.v = g[2]; D2.v = g[3];
        unsigned int o4[4];
#pragma unroll
        for (int j = 0; j < 4; ++j) {
            f32x2 a2 = {__uint_as_float(A.u[j] << 16),  __uint_as_float(A.u[j] & 0xffff0000u)};
            f32x2 b2 = {__uint_as_float(B2.u[j] << 16), __uint_as_float(B2.u[j] & 0xffff0000u)};
            f32x2 c2 = {__uint_as_float(C2.u[j] << 16), __uint_as_float(C2.u[j] & 0xffff0000u)};
            f32x2 d2 = {__uint_as_float(D2.u[j] << 16), __uint_as_float(D2.u[j] & 0xffff0000u)};
            f32x2 v2 = a2 * w0 + b2 * w1 + c2 * w2 + d2 * w3;   // v_pk_fma_f32
            unsigned int pk;
            asm("v_cvt_pk_bf16_f32 %0, %1, %2" : "=v"(pk) : "v"(v2.x), "v"(v2.y));
            o4[j] = pk;
        }
        *(uint4*)&vbuf[vslot] = make_uint4(o4[0], o4[1], o4[2], o4[3]);
    };

    f32x4 acc[4][2] = {};

    auto compute = [&](int slot) {
#pragma unroll
        for (int ks = 0; ks < 2; ++ks) {
            int s = (ks << 2) + kg;
            bf16x8 aF[4], bF[2];
#pragma unroll
            for (int i = 0; i < 4; ++i) {
                int o = (wo << 6) + (i << 4) + m16;
                aF[i] = *(const bf16x8*)&wbuf[slot][(o << 6) + ((s ^ (o & 7)) << 3)];
            }
#pragma unroll
            for (int j = 0; j < 2; ++j) {
                int p = (wp << 5) + (j << 4) + m16;   // 0..63
                bF[j] = *(const bf16x8*)&vbuf[(p << 6) + ((s ^ (p & 7)) << 3)];
            }
#pragma unroll
            for (int i = 0; i < 4; ++i)
#pragma unroll
                for (int j = 0; j < 2; ++j)
                    acc[i][j] = __builtin_amdgcn_mfma_f32_16x16x32_bf16(
                        aF[i], bF[j], acc[i][j], 0, 0, 0);
        }
    };

    uint4 gA[4], gB[4];

    __syncthreads();            // coords visible
    gather(0, gA);
    stage_w(0, 0);

#define HALFSTEP(CUR, GCUR, GNXT, NW1, NW2)                              \
    __builtin_amdgcn_s_barrier();                                        \
    asm volatile("" ::: "memory");                                       \
    if ((CUR) + 1 < 18) { gather((CUR) + 1, GNXT); stage_w((CUR) + 1, ((CUR) + 1) & 1); } \
    asm volatile("s_waitcnt vmcnt(" #NW1 ")" ::: "memory");              \
    finish((CUR), GCUR);                                                 \
    asm volatile("s_waitcnt vmcnt(" #NW2 ") lgkmcnt(0)" ::: "memory");   \
    __builtin_amdgcn_s_barrier();                                        \
    asm volatile("" ::: "memory");                                       \
    __builtin_amdgcn_s_setprio(1);                                       \
    compute((CUR) & 1);                                                  \
    __builtin_amdgcn_s_setprio(0);

    for (int c = 0; c < 16; c += 2) {
        HALFSTEP(c, gA, gB, 12, 8)
        HALFSTEP(c + 1, gB, gA, 12, 8)
    }
    HALFSTEP(16, gA, gB, 12, 8)
    HALFSTEP(17, gB, gA, 4, 0)
#undef HALFSTEP

    // partial write: part[half][b][o][p], bf16, no bias
    unsigned short* pd = part + (((size_t)((half << 2) + b)) << 20);
#pragma unroll
    for (int i = 0; i < 4; ++i) {
        int ob = (wo << 6) + (i << 4) + (kg << 2);
#pragma unroll
        for (int j = 0; j < 2; ++j) {
            int p = pix0 + (wp << 5) + (j << 4) + m16;
#pragma unroll
            for (int r = 0; r < 4; ++r) {
                int oo = ob + r;
                pd[(((size_t)oo) << 12) + p] = f32_to_bf16(acc[i][j][r]);
            }
        }
    }
}

// ---------------------------------------------------------------------------
// Kernel 4: combine bf16 partials + bias: out = p0 + p1 + b_dcn[o]. f32 out.
// grid 2048 x 256 thr, 8 elems/thread.
// ---------------------------------------------------------------------------
__global__ __launch_bounds__(256) void combine_out(
    const unsigned short* __restrict__ part, const float* __restrict__ b_dcn,
    float* __restrict__ out) {
    int i = (blockIdx.x * 256 + threadIdx.x) << 3;
    float bias = b_dcn[(i >> 12) & 255];
    union { uint4 v; unsigned int u[4]; } A, B2;
    A.v  = *(const uint4*)(part + i);
    B2.v = *(const uint4*)(part + ((size_t)4 << 20) + i);
    float r[8];
#pragma unroll
    for (int j = 0; j < 4; ++j) {
        float a_lo = __uint_as_float(A.u[j] << 16);
        float a_hi = __uint_as_float(A.u[j] & 0xffff0000u);
        float b_lo = __uint_as_float(B2.u[j] << 16);
        float b_hi = __uint_as_float(B2.u[j] & 0xffff0000u);
        r[2 * j]     = a_lo + b_lo + bias;
        r[2 * j + 1] = a_hi + b_hi + bias;
    }
    *(float4*)(out + i)     = make_float4(r[0], r[1], r[2], r[3]);
    *(float4*)(out + i + 4) = make_float4(r[4], r[5], r[6], r[7]);
}

// ---------------------------------------------------------------------------
extern "C" void kernel_launch(void* const* d_in, const int* in_sizes, int n_in,
                              void* d_out, int out_size, void* d_ws, size_t ws_size,
                              hipStream_t stream) {
    const float* x      = (const float*)d_in[0];
    const float* w_off  = (const float*)d_in[1];
    const float* b_off  = (const float*)d_in[2];
    const float* w_mask = (const float*)d_in[3];
    const float* b_mask = (const float*)d_in[4];
    const float* w_dcn  = (const float*)d_in[5];
    const float* b_dcn  = (const float*)d_in[6];
    float* out = (float*)d_out;

    float* ws = (float*)d_ws;
    float* offmask = ws;                                       //  1.77 MB
    unsigned short* xTh = (unsigned short*)(offmask + (size_t)B_ * NCH_ * HW_); // 8.39 MB
    unsigned short* wTs = xTh + ((size_t)B_ * HW_ * C_);       //  1.18 MB
    unsigned short* wCs = wTs + (size_t)36 * 16384;            //  0.15 MB
    unsigned short* part = wCs + (size_t)36 * 2048;            // 16.78 MB (2 halves, bf16)
    // total ~28.3 MB of d_ws

    prep_all<<<dim3(4384), dim3(256), 0, stream>>>(x, xTh, w_dcn, w_off, w_mask, wTs, wCs);
    conv_mfma<<<dim3(512), dim3(256), 0, stream>>>(xTh, wCs, b_off, b_mask, offmask);
    dcn_fused<<<dim3(512), dim3(512), 0, stream>>>(xTh, offmask, wTs, part);
    combine_out<<<dim3(2048), dim3(256), 0, stream>>>(part, b_dcn, out);
}